// Round 7
// baseline (162.172 us; speedup 1.0000x reference)
//
#include <hip/hip_runtime.h>
#include <hip/hip_bf16.h>
#include <math.h>

typedef __bf16 bf16x8 __attribute__((ext_vector_type(8)));
typedef __bf16 bf16x4 __attribute__((ext_vector_type(4)));
typedef __bf16 bf16x2 __attribute__((ext_vector_type(2)));
typedef float  f32x4  __attribute__((ext_vector_type(4)));
typedef float  f32x16 __attribute__((ext_vector_type(16)));
typedef unsigned int u32;
typedef unsigned int u32x4 __attribute__((ext_vector_type(4)));

#define HD   64
#define MNEG (-1e30f)  // finite "-inf": exp2f(MNEG - x) == 0, no NaN possible
// XOR swizzles (element-space) for 128B-stride rows; write & read sides agree
#define KSW(r, c) ((c) ^ (((r) & 7) << 3))
#define VSW(r, c) ((c) ^ ((((r) >> 2) & 7) << 3))

#define NSLOT   1024                 // 32 bh x 16 x-blocks x 2 kv-chunks
#define ACC_FL  (NSLOT * 8192)       // f32 per-slot 128q x 64d
#define ML_FL   (NSLOT * 256)        // m[128], l[128] per slot
#define WS_NEED ((size_t)(ACC_FL + ML_FL) * 4)

static __device__ __forceinline__ u32 pkbf(float a, float b) {
  bf16x2 t; t[0] = (__bf16)a; t[1] = (__bf16)b;
  return __builtin_bit_cast(u32, t);
}

template <int SPLIT>
__global__ __launch_bounds__(256, 2)
void fattn_fwd(const float* __restrict__ Q, const float* __restrict__ K,
               const float* __restrict__ V, const int* __restrict__ causal_p,
               float* __restrict__ O, float* __restrict__ wsAcc,
               float* __restrict__ wsML, int B, int N, int H) {
  __shared__ alignas(16) __bf16 Kl[2][64][64];   // K[kv][d], swizzled cols
  __shared__ alignas(16) __bf16 Vt[2][64][64];   // V^T[d][kv], swizzled cols

  const int tid  = threadIdx.x;
  const int wave = tid >> 6;
  const int lane = tid & 63;
  const int l31  = lane & 31;
  const int h    = lane >> 5;        // 32-lane half
  const int lo16 = lane & 15, hi4 = lane >> 4;

  const int causal = causal_p[0];

  // ---- work mapping: heavy chunks first (LPT) ----
  int x, bh, t0, t1, slot = 0;
  if constexpr (SPLIT) {
    bh = (int)blockIdx.x & 31;
    const int xc = (int)blockIdx.x >> 5;   // 0..31
    x = 15 - (xc >> 1);
    const int c = xc & 1;
    const int ntile = causal ? (2 * x + 2) : 32;
    t0 = c * 16;
    t1 = min(t0 + 16, ntile);
    if (t0 >= t1) return;                  // empty chunk (causal, small x)
    slot = (bh * 16 + x) * 2 + c;
  } else {
    x  = 15 - ((int)blockIdx.x >> 5);
    bh = (int)blockIdx.x & 31;
    t0 = 0;
    t1 = causal ? (2 * x + 2) : 32;
  }
  const int bb = bh / H, hh = bh - bb * H;
  const int sN = H * HD;

  const float* Qb = Q + (long)bb * N * sN + hh * HD;
  const float* Kb = K + (long)bb * N * sN + hh * HD;
  const float* Vb = V + (long)bb * N * sN + hh * HD;
  float*       Ob = O + (long)bb * N * sN + hh * HD;

  const int q0w = x * 128 + wave * 32;     // this wave's q-rows

  // ---- Q fragments (B-operand: col=q=lane&31, k = h*8+0..7 per d-slice) ----
  const float qscale = 0.125f * 1.44269504088896340736f;  // 1/sqrt(64)*log2e
  bf16x8 aq[4];
  {
    const float* qrow = Qb + (long)(q0w + l31) * sN;
#pragma unroll
    for (int ds = 0; ds < 4; ++ds) {
      f32x4 x0 = *(const f32x4*)(qrow + ds * 16 + h * 8);
      f32x4 x1 = *(const f32x4*)(qrow + ds * 16 + h * 8 + 4);
      bf16x8 a;
#pragma unroll
      for (int j = 0; j < 4; ++j) {
        a[j]     = (__bf16)(x0[j] * qscale);
        a[j + 4] = (__bf16)(x1[j] * qscale);
      }
      aq[ds] = a;
    }
  }

  // O^T accumulators: col=q=lane&31 (one q per lane), rows=d
  f32x16 accA, accB;
#pragma unroll
  for (int j = 0; j < 16; ++j) { accA[j] = 0.f; accB[j] = 0.f; }
  float m_run = MNEG, l_run = 0.f;

  // ---- staging: global f32 -> regs (issue), regs -> bf16 LDS (wr) ----
  f32x4 kreg[4], vreg[4];
  auto issue = [&](int tt) {
    const int k0 = tt * 64;
#pragma unroll
    for (int i = 0; i < 4; ++i) {
      const int fl = tid + i * 256;
      const int r = fl >> 4, c4 = (fl & 15) * 4;
      kreg[i] = *(const f32x4*)(Kb + (long)(k0 + r) * sN + c4);
    }
    // V: lane owns 4x4 (kv x d) block -> free in-register transpose
    const float* vrow = Vb + (long)(k0 + wave * 16 + hi4 * 4) * sN + lo16 * 4;
#pragma unroll
    for (int q = 0; q < 4; ++q) vreg[q] = *(const f32x4*)(vrow + (long)q * sN);
  };
  auto wr = [&](int buf) {
#pragma unroll
    for (int i = 0; i < 4; ++i) {
      const int fl = tid + i * 256;
      const int r = fl >> 4, c4 = (fl & 15) * 4;
      bf16x4 kb;
#pragma unroll
      for (int j = 0; j < 4; ++j) kb[j] = (__bf16)kreg[i][j];
      *(bf16x4*)&Kl[buf][r][KSW(r, c4)] = kb;
    }
    const int kv0 = wave * 16 + hi4 * 4;
#pragma unroll
    for (int j = 0; j < 4; ++j) {
      const int d = lo16 * 4 + j;
      bf16x4 vv;
#pragma unroll
      for (int q = 0; q < 4; ++q) vv[q] = (__bf16)vreg[q][j];
      *(bf16x4*)&Vt[buf][d][VSW(d, kv0)] = vv;
    }
  };

  issue(t0);
  wr(0);
  __syncthreads();

  int pb = 0;
  for (int t = t0; t < t1; ++t) {
    const bool pf = (t + 1 < t1);
    if (pf) issue(t + 1);            // T14: loads in flight under compute
    const int k0 = t * 64;

    // ---- S^T = K (A, rows=kv) x Q^T (B, cols=q) ----
    f32x16 p0, p1;
#pragma unroll
    for (int j = 0; j < 16; ++j) { p0[j] = 0.f; p1[j] = 0.f; }
#pragma unroll
    for (int ds = 0; ds < 4; ++ds) {
      const int cc = ds * 16 + h * 8;
      bf16x8 ka = *(const bf16x8*)&Kl[pb][l31][KSW(l31, cc)];
      p0 = __builtin_amdgcn_mfma_f32_32x32x16_bf16(ka, aq[ds], p0, 0, 0, 0);
      bf16x8 kb2 = *(const bf16x8*)&Kl[pb][32 + l31][KSW(32 + l31, cc)];
      p1 = __builtin_amdgcn_mfma_f32_32x32x16_bf16(kb2, aq[ds], p1, 0, 0, 0);
    }

    // ---- causal mask (diagonal tiles t = 2x, 2x+1 only) ----
    if (causal && t >= 2 * x) {
      const int qg = q0w + l31;
#pragma unroll
      for (int reg = 0; reg < 16; ++reg) {
        const int crow = (reg & 3) + 8 * (reg >> 2) + 4 * h;
        if (k0 + crow > qg)      p0[reg] = MNEG;
        if (k0 + 32 + crow > qg) p1[reg] = MNEG;
      }
    }

    // ---- online softmax: in-lane trees + one cross-half shuffle ----
    float t8[8];
#pragma unroll
    for (int j = 0; j < 8; ++j)
      t8[j] = fmaxf(fmaxf(p0[j], p0[j + 8]), fmaxf(p1[j], p1[j + 8]));
#pragma unroll
    for (int stp = 4; stp > 0; stp >>= 1)
#pragma unroll
      for (int j = 0; j < stp; ++j) t8[j] = fmaxf(t8[j], t8[j + stp]);
    const float mx = fmaxf(t8[0], __shfl_xor(t8[0], 32));
    // T13 defer-max: skip rescale while max growth <= 8 (p bounded by 2^8)
    if (!__all(mx - m_run <= 8.0f)) {
      const float mnew = fmaxf(m_run, mx);
      const float fac  = exp2f(m_run - mnew);   // first tile: 0
      l_run *= fac;
      m_run = mnew;
#pragma unroll
      for (int j = 0; j < 16; ++j) { accA[j] *= fac; accB[j] *= fac; }
    }
#pragma unroll
    for (int j = 0; j < 16; ++j) {
      p0[j] = exp2f(p0[j] - m_run);             // masked MNEG -> 0
      p1[j] = exp2f(p1[j] - m_run);
    }
    float s8[8];
#pragma unroll
    for (int j = 0; j < 8; ++j)
      s8[j] = (p0[j] + p0[j + 8]) + (p1[j] + p1[j + 8]);
#pragma unroll
    for (int stp = 4; stp > 0; stp >>= 1)
#pragma unroll
      for (int j = 0; j < stp; ++j) s8[j] += s8[j + stp];
    const float ps = s8[0] + __shfl_xor(s8[0], 32);
    l_run += ps;

    // ---- P^T B-fragments in-register: pack bf16x2 words, exchange halves ----
    u32 W0[8], W1[8];
#pragma unroll
    for (int tt = 0; tt < 8; ++tt) {
      W0[tt] = pkbf(p0[2 * tt], p0[2 * tt + 1]);
      W1[tt] = pkbf(p1[2 * tt], p1[2 * tt + 1]);
    }
    auto mkpair = [&](u32 wa, u32 wb, u32& dlo, u32& dhi) {
      const u32 gsel = h ? wa : wb;             // what the other half needs
      const u32 f = (u32)__shfl_xor((int)gsel, 32);
      dlo = h ? f : wa;
      dhi = h ? wb : f;
    };
    bf16x8 pa[4];
    {
      u32 d0, d1, d2, d3;
      mkpair(W0[0], W0[2], d0, d2); mkpair(W0[1], W0[3], d1, d3);
      pa[0] = __builtin_bit_cast(bf16x8, (u32x4){d0, d1, d2, d3});
      mkpair(W0[4], W0[6], d0, d2); mkpair(W0[5], W0[7], d1, d3);
      pa[1] = __builtin_bit_cast(bf16x8, (u32x4){d0, d1, d2, d3});
      mkpair(W1[0], W1[2], d0, d2); mkpair(W1[1], W1[3], d1, d3);
      pa[2] = __builtin_bit_cast(bf16x8, (u32x4){d0, d1, d2, d3});
      mkpair(W1[4], W1[6], d0, d2); mkpair(W1[5], W1[7], d1, d3);
      pa[3] = __builtin_bit_cast(bf16x8, (u32x4){d0, d1, d2, d3});
    }

    // ---- O^T += V^T (A, rows=d) x P^T (B, cols=q) ----
#pragma unroll
    for (int ks = 0; ks < 4; ++ks) {
      bf16x8 va = *(const bf16x8*)&Vt[pb][l31][VSW(l31, ks * 16 + h * 8)];
      accA = __builtin_amdgcn_mfma_f32_32x32x16_bf16(va, pa[ks], accA, 0, 0, 0);
    }
#pragma unroll
    for (int ks = 0; ks < 4; ++ks) {
      bf16x8 va = *(const bf16x8*)&Vt[pb][32 + l31][VSW(32 + l31, ks * 16 + h * 8)];
      accB = __builtin_amdgcn_mfma_f32_32x32x16_bf16(va, pa[ks], accB, 0, 0, 0);
    }

    if (pf) wr(pb ^ 1);    // stage t+1 into the idle buffer
    __syncthreads();       // staged buffer visible; reads of pb done
    pb ^= 1;
  }

  // ---- epilogue ----
  const int qrel = wave * 32 + l31;
  if constexpr (SPLIT) {
    float* ap = wsAcc + (long)slot * 8192 + qrel * 64;
#pragma unroll
    for (int g = 0; g < 4; ++g) {
      f32x4 o0, o1;
#pragma unroll
      for (int j = 0; j < 4; ++j) { o0[j] = accA[4 * g + j]; o1[j] = accB[4 * g + j]; }
      *(f32x4*)(ap + 8 * g + 4 * h) = o0;
      *(f32x4*)(ap + 32 + 8 * g + 4 * h) = o1;
    }
    if (h == 0) {
      wsML[slot * 256 + qrel] = m_run;
      wsML[slot * 256 + 128 + qrel] = l_run;
    }
  } else {
    const float linv = 1.0f / l_run;
    float* orow = Ob + (long)(q0w + l31) * sN;
#pragma unroll
    for (int g = 0; g < 4; ++g) {
      f32x4 o0, o1;
#pragma unroll
      for (int j = 0; j < 4; ++j) {
        o0[j] = accA[4 * g + j] * linv;
        o1[j] = accB[4 * g + j] * linv;
      }
      *(f32x4*)(orow + 8 * g + 4 * h) = o0;
      *(f32x4*)(orow + 32 + 8 * g + 4 * h) = o1;
    }
  }
}

__global__ __launch_bounds__(256)
void fmerge(const float* __restrict__ wsAcc, const float* __restrict__ wsML,
            const int* __restrict__ causal_p, float* __restrict__ O,
            int B, int N, int H) {
  const int tid = threadIdx.x;
  const int bh = (int)blockIdx.x >> 4;    // 0..31
  const int x  = (int)blockIdx.x & 15;
  const int bb = bh / H, hh = bh - bb * H;
  const int causal = causal_p[0];
  const int ntile = causal ? (2 * x + 2) : 32;
  const int q  = tid >> 1;                // 0..127
  const int dh = (tid & 1) * 32;
  const int slot0 = (bh * 16 + x) * 2;
  const bool v1 = (16 < ntile);           // second chunk exists?

  const float m0 = wsML[slot0 * 256 + q];
  const float l0 = wsML[slot0 * 256 + 128 + q];
  const float m1 = v1 ? wsML[(slot0 + 1) * 256 + q] : MNEG;
  const float l1 = v1 ? wsML[(slot0 + 1) * 256 + 128 + q] : 0.f;
  const float M  = fmaxf(m0, m1);
  const float e0 = exp2f(m0 - M);
  const float e1 = v1 ? exp2f(m1 - M) : 0.f;
  const float inv = 1.0f / (e0 * l0 + e1 * l1);
  const float f0 = e0 * inv, f1 = e1 * inv;

  const float* a0 = wsAcc + (long)slot0 * 8192 + q * 64 + dh;
  const float* a1 = a0 + 8192;
  float* op = O + ((long)(bb * N + x * 128 + q) * H + hh) * HD + dh;
#pragma unroll
  for (int j = 0; j < 8; ++j) {
    f32x4 r0 = *(const f32x4*)(a0 + 4 * j);
    f32x4 o;
#pragma unroll
    for (int e = 0; e < 4; ++e) o[e] = r0[e] * f0;
    if (v1) {
      f32x4 r1 = *(const f32x4*)(a1 + 4 * j);
#pragma unroll
      for (int e = 0; e < 4; ++e) o[e] += r1[e] * f1;
    }
    *(f32x4*)(op + 4 * j) = o;
  }
}

extern "C" void kernel_launch(void* const* d_in, const int* in_sizes, int n_in,
                              void* d_out, int out_size, void* d_ws, size_t ws_size,
                              hipStream_t stream) {
  const float* q = (const float*)d_in[0];
  const float* k = (const float*)d_in[1];
  const float* v = (const float*)d_in[2];
  const int* causal = (const int*)d_in[3];
  float* out = (float*)d_out;
  const int B = 2, N = 2048, H = 16;
  if (ws_size >= WS_NEED) {
    float* wsAcc = (float*)d_ws;
    float* wsML  = wsAcc + ACC_FL;
    fattn_fwd<1><<<dim3(NSLOT), dim3(256), 0, stream>>>(q, k, v, causal, out,
                                                        wsAcc, wsML, B, N, H);
    fmerge<<<dim3(512), dim3(256), 0, stream>>>(wsAcc, wsML, causal, out, B, N, H);
  } else {
    fattn_fwd<0><<<dim3(512), dim3(256), 0, stream>>>(q, k, v, causal, out,
                                                      nullptr, nullptr, B, N, H);
  }
}